// Round 4
// baseline (72.704 us; speedup 1.0000x reference)
//
#include <hip/hip_runtime.h>
#include <hip/hip_bf16.h>
#include <stdint.h>

// KANLinear: y[b,o] = sum_{d,k} coeff[b,d,k]*values[o,d,k] + xc@skip_w^T + skip_b
// Reformulated: Vp[o,d*16+k] = values[o,d,k] + grid[k]*skip_w[o,d]  (prep)
//               y = A @ Vp^T + skip_b  (bf16 MFMA GEMM, M=8192 N=256 K=4096)
// Round 4: A built IN REGISTERS from a 16KB packed coeff table (no A-LDS
//          round trip); LDS holds only B (48KB total -> 3 blocks/CU,
//          12 waves/CU); K-split 8, BK=64, BM=BN=128, 4 waves of 64x64.

#define D_DIM  256
#define O_DIM  256
#define BM     128
#define BN     128
#define BK     64
#define KSPLIT 8
#define ITERS  8             // (4096/KSPLIT)/BK
#define NTHREADS 256

typedef __attribute__((ext_vector_type(8))) short bf16x8;
typedef __attribute__((ext_vector_type(4))) float f32x4;

static __device__ __forceinline__ unsigned short f2bf(float f) {
    unsigned int u = __float_as_uint(f);
    u += 0x7fffu + ((u >> 16) & 1u);   // RNE
    return (unsigned short)(u >> 16);
}

// ---------------------------------------------------------------------------
// Prep: Vp[o][kflat] = values[o][d][k] + grid[k]*skip_w[o][d], bf16.
// Layout: tile (ntile = o>>7, kt = kflat>>6) = 128 rows(n=o&127) x 64 cols,
// 1024 chunks of 16B; chunk (n, k8=(kflat>>3)&7) at slot n*8 + (k8^(n&7)).
// (unchanged from round 3 - proven correct)
// ---------------------------------------------------------------------------
__global__ __launch_bounds__(256) void kan_prep(
    const float* __restrict__ values,   // [O][D][K]
    const float* __restrict__ skip_w,   // [O][D]
    const float* __restrict__ gknots,   // [K]
    unsigned short* __restrict__ Vp)    // 2 MB bf16, swizzled-tiled
{
    int tid = blockIdx.x * blockDim.x + threadIdx.x;    // 0..131071
    int e = tid * 8;
    int o = e >> 12;
    int kflat = e & 4095;
    float sw = skip_w[(o << 8) | (kflat >> 4)];
    int kmod = kflat & 15;                              // 0 or 8

    const float4* vp4 = reinterpret_cast<const float4*>(values + e);
    float4 v0 = vp4[0], v1 = vp4[1];
    float f[8] = {v0.x, v0.y, v0.z, v0.w, v1.x, v1.y, v1.z, v1.w};
    unsigned int w[4];
#pragma unroll
    for (int j = 0; j < 4; ++j) {
        float2 ab;
        ab.x = f[2*j]     + gknots[kmod + 2*j]     * sw;
        ab.y = f[2*j + 1] + gknots[kmod + 2*j + 1] * sw;
        __hip_bfloat162 p2 = __float22bfloat162_rn(ab);
        __builtin_memcpy(&w[j], &p2, 4);
    }

    int ntile = o >> 7, n = o & 127;
    int kt = kflat >> 6, k8 = (kflat >> 3) & 7;
    int slot = n * 8 + (k8 ^ (n & 7));
    size_t dst = ((size_t)(ntile * 64 + kt) * 1024 + (size_t)slot) * 8;
    *reinterpret_cast<uint4*>(Vp + dst) = make_uint4(w[0], w[1], w[2], w[3]);
}

// ---------------------------------------------------------------------------
// GEMM: BM=BN=128, BK=64, 4 waves each owning 64x64 (acc[4][4]).
// A-fragments built in registers from Pk LDS table; B double-buffered via
// global_load_lds; K-split 8 with f32 atomic combine.
// ---------------------------------------------------------------------------
__global__ __launch_bounds__(NTHREADS, 3) void kan_gemm(
    const float* __restrict__ x,          // [B][D] f32
    const unsigned short* __restrict__ Vp,
    const float* __restrict__ skip_b,     // [O]
    float* __restrict__ out)              // [B][O] f32 (zero-initialized)
{
    __shared__ unsigned short Bs[2][BN * BK];   // 2 x 16 KB
    __shared__ unsigned int Pk[BM * 32];        // 16 KB: [row][d^swz] packed {bf16 w, li}

    const int t    = threadIdx.x;
    const int lane = t & 63;
    const int wid  = t >> 6;
    const int wm   = wid >> 1;         // wave row 0..1 (64 rows each)
    const int wn   = wid & 1;          // wave col 0..1 (64 cols each)
    const int l15  = lane & 15;
    const int lhi  = lane >> 4;        // 0..3
    const int h    = lhi >> 1;         // d sub-select within k-step
    const int kb   = (lhi & 1) * 8;    // knot-half base (0 or 8)

    const int bid = (int)blockIdx.x;
    const int ks  = bid & 7;                       // K-split slice
    const int nt  = (bid >> 3) & 1;                // N tile
    const int mt  = bid >> 4;                      // M tile 0..63
    const int bm0 = mt * BM;
    const int oc0 = nt * BN;
    const int g0  = ks * ITERS;                    // global BK-tile base

    // ---- prologue part 1: build Pk coefficient tile (16 elems/thread)
    {
        int row = t >> 1;                 // 0..127
        int dc0 = (t & 1) * 16;           // 0 or 16
        const float* xr = x + (size_t)(bm0 + row) * D_DIM + ks * 32 + dc0;
        int swz = (row & 7) << 2;
#pragma unroll
        for (int j = 0; j < 4; ++j) {
            float4 v = reinterpret_cast<const float4*>(xr)[j];
            float vv[4] = {v.x, v.y, v.z, v.w};
#pragma unroll
            for (int e = 0; e < 4; ++e) {
                float xc = fminf(1.f, fmaxf(-1.f, vv[e]));
                float tt = (xc + 1.f) * 7.5f;     // (xc - g0)/h, h = 2/15
                int li = (int)tt;
                li = li > 14 ? 14 : li;
                float w1 = tt - (float)li;
                unsigned int q = ((unsigned int)f2bf(w1) << 16) | (unsigned int)li;
                int d = dc0 + j * 4 + e;
                Pk[row * 32 + (d ^ swz)] = q;
            }
        }
    }

    auto stageB = [&](int buf, int ktg) {
        const char* tb = (const char*)(Vp + ((size_t)(nt * 64 + ktg)) * 8192);
        char* lb = (char*)&Bs[buf][0];
#pragma unroll
        for (int r = 0; r < 4; ++r) {
            const char* g = tb + (r * 256 + t) * 16;
            unsigned ldsoff = (unsigned)((r * 256 + wid * 64) * 16);  // wave-uniform
            __builtin_amdgcn_global_load_lds(
                (const __attribute__((address_space(1))) unsigned int*)g,
                (__attribute__((address_space(3))) unsigned int*)(lb + ldsoff),
                16, 0, 0);
        }
    };

    // ---- prologue part 2: stage first B tile, one barrier covers both
    stageB(0, g0);
    __syncthreads();

    // per-thread fragment constants
    int apkb[4], aswz[4];
#pragma unroll
    for (int mi = 0; mi < 4; ++mi) {
        int row = wm * 64 + mi * 16 + l15;
        apkb[mi] = row * 32;
        aswz[mi] = (row & 7) << 2;
    }
    int nbyte[4], n7[4];
#pragma unroll
    for (int ni = 0; ni < 4; ++ni) {
        int n = wn * 64 + ni * 16 + l15;
        nbyte[ni] = n * 128;
        n7[ni] = n & 7;
    }

    f32x4 acc[4][4] = {};

    for (int kt = 0; kt < ITERS; ++kt) {
        const int cur = kt & 1;
        if (kt + 1 < ITERS) stageB(cur ^ 1, g0 + kt + 1);
        const char* Bb = (const char*)&Bs[cur][0];

#pragma unroll
        for (int kh = 0; kh < 2; ++kh) {
            // B fragments: 4 swizzled ds_read_b128
            bf16x8 bg[4];
            int k8 = kh * 4 + lhi;
#pragma unroll
            for (int ni = 0; ni < 4; ++ni)
                bg[ni] = *reinterpret_cast<const bf16x8*>(
                    Bb + nbyte[ni] + ((k8 ^ n7[ni]) << 4));

            // A fragments: in-register build from Pk
            bf16x8 af[4];
            int dl = kt * 4 + kh * 2 + h;
#pragma unroll
            for (int mi = 0; mi < 4; ++mi) {
                unsigned int q = Pk[apkb[mi] + (dl ^ aswz[mi])];
                float c1 = __uint_as_float(q & 0xffff0000u);   // bf16 w -> f32
                float c0 = 1.f - c1;
                float2 cc; cc.x = c0; cc.y = c1;
                __hip_bfloat162 p2 = __float22bfloat162_rn(cc); // v_cvt_pk_bf16_f32
                unsigned int pk; __builtin_memcpy(&pk, &p2, 4);
                int li = (int)(q & 15u);
                int lp = li - kb;                               // knot pos in this half
                unsigned long long w64 =
                    (unsigned long long)pk << ((li & 1) * 16);
                unsigned int lo = (unsigned int)w64;
                unsigned int hi = (unsigned int)(w64 >> 32);
                int jl = lp >> 1;                               // arithmetic shift
                unsigned int wd[4];
#pragma unroll
                for (int j2 = 0; j2 < 4; ++j2)
                    wd[j2] = (jl == j2) ? lo : ((jl == j2 - 1) ? hi : 0u);
                uint4 u = make_uint4(wd[0], wd[1], wd[2], wd[3]);
                __builtin_memcpy(&af[mi], &u, 16);
            }

            // 16 MFMA
#pragma unroll
            for (int mi = 0; mi < 4; ++mi)
#pragma unroll
                for (int ni = 0; ni < 4; ++ni)
                    acc[mi][ni] = __builtin_amdgcn_mfma_f32_16x16x32_bf16(
                        af[mi], bg[ni], acc[mi][ni], 0, 0, 0);
        }
        __syncthreads();
    }

    // ---- epilogue: atomic combine of K-split partials (+ skip_b once)
#pragma unroll
    for (int ni = 0; ni < 4; ++ni) {
        int col = oc0 + wn * 64 + ni * 16 + l15;
        float sb = (ks == 0) ? skip_b[col] : 0.f;
#pragma unroll
        for (int mi = 0; mi < 4; ++mi) {
            f32x4 v = acc[mi][ni];
            int row0 = bm0 + wm * 64 + mi * 16 + lhi * 4;
#pragma unroll
            for (int r = 0; r < 4; ++r)
                unsafeAtomicAdd(&out[(size_t)(row0 + r) * O_DIM + col], v[r] + sb);
        }
    }
}

extern "C" void kernel_launch(void* const* d_in, const int* in_sizes, int n_in,
                              void* d_out, int out_size, void* d_ws, size_t ws_size,
                              hipStream_t stream) {
    const float* x      = (const float*)d_in[0];   // [8192][256]
    const float* values = (const float*)d_in[1];   // [256][256][16]
    const float* skip_w = (const float*)d_in[2];   // [256][256]
    const float* skip_b = (const float*)d_in[3];   // [256]
    const float* gknots = (const float*)d_in[4];   // [16]
    float* out = (float*)d_out;
    unsigned short* Vp = (unsigned short*)d_ws;    // 2 MB bf16 scratch
    (void)in_sizes; (void)n_in; (void)out_size; (void)ws_size;

    // K-split partials are atomically accumulated -> out must start at zero.
    hipMemsetAsync(out, 0, (size_t)8192 * 256 * sizeof(float), stream);

    // Prep: 1,048,576 elements, 8 per thread
    kan_prep<<<dim3(512), dim3(256), 0, stream>>>(values, skip_w, gknots, Vp);

    // GEMM: 64 M-tiles x 2 N-tiles x 8 K-splits = 1024 blocks (3/CU resident)
    kan_gemm<<<dim3(1024), dim3(NTHREADS), 0, stream>>>(x, Vp, skip_b, out);
}

// Round 5
// 62.797 us; speedup vs baseline: 1.1578x; 1.1578x over previous
//
#include <hip/hip_runtime.h>
#include <hip/hip_bf16.h>
#include <stdint.h>

// KANLinear: y[b,o] = sum_{d,k} coeff[b,d,k]*values[o,d,k] + xc@skip_w^T + skip_b
// Reformulated: Vp[o,d*16+k] = values[o,d,k] + grid[k]*skip_w[o,d]  (prep)
//               y = A @ Vp^T + skip_b  (bf16 MFMA GEMM, M=8192 N=256 K=4096)
// Round 5: NO K-split / NO atomics (R3/R4's regression was the atomic tax:
//          WRITE_SIZE tracked 8.4M->16.8M atomics). BM=128 BN=64 BK=64,
//          4 waves of 64x32, grid 256 = 1 block/CU. Counted-vmcnt pipeline
//          (asm s_waitcnt vmcnt(1) + raw s_barrier) instead of __syncthreads'
//          vmcnt(0) drain; A staged via LDS once per tile (distributed build).

#define D_DIM  256
#define O_DIM  256
#define BM     128
#define BN     64
#define BK     64
#define ITERS  64            // 4096 / BK
#define NTHREADS 256

typedef __attribute__((ext_vector_type(8))) short bf16x8;
typedef __attribute__((ext_vector_type(4))) float f32x4;

// ---------------------------------------------------------------------------
// Prep (R1-proven): Vp[o][kflat] = values[o][d][k] + grid[k]*skip_w[o][d],
// bf16, tile-blocked 64 rows x 64 cols, XOR-pre-swizzled:
// tile (cblk=o>>6, kt=kflat>>6): chunk (n=o&63, k8=(kflat>>3)&7) at slot
// n*8 + (k8^(n&7)). GEMM B-staging is then a linear global_load_lds copy and
// swizzled ds_read_b128 is bank-conflict-free.
// ---------------------------------------------------------------------------
__global__ __launch_bounds__(256) void kan_prep(
    const float* __restrict__ values,   // [O][D][K]
    const float* __restrict__ skip_w,   // [O][D]
    const float* __restrict__ gknots,   // [K]
    unsigned short* __restrict__ Vp)    // 2 MB bf16, swizzled-tiled
{
    int tid = blockIdx.x * blockDim.x + threadIdx.x;    // 0..131071
    int e = tid * 8;
    int o = e >> 12;
    int kflat = e & 4095;
    float sw = skip_w[(o << 8) | (kflat >> 4)];
    int kmod = kflat & 15;                              // 0 or 8

    const float4* vp4 = reinterpret_cast<const float4*>(values + e);
    float4 v0 = vp4[0], v1 = vp4[1];
    float f[8] = {v0.x, v0.y, v0.z, v0.w, v1.x, v1.y, v1.z, v1.w};
    unsigned int w[4];
#pragma unroll
    for (int j = 0; j < 4; ++j) {
        float2 ab;
        ab.x = f[2*j]     + gknots[kmod + 2*j]     * sw;
        ab.y = f[2*j + 1] + gknots[kmod + 2*j + 1] * sw;
        __hip_bfloat162 p2 = __float22bfloat162_rn(ab);
        __builtin_memcpy(&w[j], &p2, 4);
    }

    int cblk = o >> 6, n = o & 63;
    int kt = kflat >> 6, k8 = (kflat >> 3) & 7;
    int slot = n * 8 + (k8 ^ (n & 7));
    size_t dst = (((size_t)(cblk * 64 + kt)) * 512 + (size_t)slot) * 8;
    *reinterpret_cast<uint4*>(Vp + dst) = make_uint4(w[0], w[1], w[2], w[3]);
}

// ---------------------------------------------------------------------------
// GEMM
// ---------------------------------------------------------------------------
__global__ __launch_bounds__(NTHREADS) void kan_gemm(
    const float* __restrict__ x,          // [B][D] f32
    const unsigned short* __restrict__ Vp,
    const float* __restrict__ skip_b,     // [O]
    float* __restrict__ out)              // [B][O] f32
{
    __shared__ unsigned short As[2][BM * BK];   // 2 x 16 KB
    __shared__ unsigned short Bs[2][BN * BK];   // 2 x 8 KB

    const int t    = threadIdx.x;
    const int lane = t & 63;
    const int wid  = t >> 6;
    const int wm   = wid >> 1;         // wave row 0..1 (64 rows each)
    const int wn   = wid & 1;          // wave col 0..1 (32 cols each)
    const int l15  = lane & 15;
    const int lhi  = lane >> 4;        // 0..3

    const int bid = (int)blockIdx.x;
    const int mt  = bid >> 2;                      // M tile 0..63
    const int ct  = bid & 3;                       // N tile 0..3
    const int bm0 = mt * BM;
    const int oc0 = ct * BN;

    // A-stage: thread -> row ab (0..127), d-pair base ad2 (0 or 2)
    const int ab  = t >> 1;
    const int ad2 = (t & 1) * 2;
    const float* xp = x + (size_t)(bm0 + ab) * D_DIM + ad2;

    char* arow[2] = { (char*)&As[0][0] + ab * 128, (char*)&As[1][0] + ab * 128 };
    const int cs0 = ((2 * ad2)     ^ (ab & 7)) * 16;
    const int cs1 = ((2 * ad2 + 1) ^ (ab & 7)) * 16;
    const int cs2 = ((2 * ad2 + 2) ^ (ab & 7)) * 16;
    const int cs3 = ((2 * ad2 + 3) ^ (ab & 7)) * 16;

    // one x value -> 16 bf16 interp coeffs (8 dwords), pair at knots li,li+1
    auto buildwd = [&](float xv, unsigned int* wd) {
        float xc = fminf(1.f, fmaxf(-1.f, xv));
        float tt = (xc + 1.f) * 7.5f;            // (xc - g0)/h, h = 2/15
        int li = (int)tt;
        li = li > 14 ? 14 : li;
        float w1 = tt - (float)li;
        float2 cw; cw.x = 1.f - w1; cw.y = w1;
        __hip_bfloat162 p2 = __float22bfloat162_rn(cw);   // v_cvt_pk_bf16_f32
        unsigned int pk;
        __builtin_memcpy(&pk, &p2, 4);
        unsigned long long w64 = (unsigned long long)pk << ((li & 1) * 16);
        unsigned int lo = (unsigned int)w64;
        unsigned int hi = (unsigned int)(w64 >> 32);
        int jl = li >> 1;
#pragma unroll
        for (int j = 0; j < 8; ++j)
            wd[j] = (j == jl) ? lo : ((j == jl + 1) ? hi : 0u);
    };

    auto stageA = [&](int buf, float2 xv) {
        unsigned int wd[8];
        char* a = arow[buf];
        buildwd(xv.x, wd);
        *reinterpret_cast<uint4*>(a + cs0) = make_uint4(wd[0], wd[1], wd[2], wd[3]);
        *reinterpret_cast<uint4*>(a + cs1) = make_uint4(wd[4], wd[5], wd[6], wd[7]);
        buildwd(xv.y, wd);
        *reinterpret_cast<uint4*>(a + cs2) = make_uint4(wd[0], wd[1], wd[2], wd[3]);
        *reinterpret_cast<uint4*>(a + cs3) = make_uint4(wd[4], wd[5], wd[6], wd[7]);
    };

    // B tile = 8 KB = 512 chunks of 16B; 256 threads x 2 DMA insts
    auto stageB = [&](int buf, int ktile) {
        const char* tb = (const char*)(Vp + ((size_t)(ct * 64 + ktile)) * 4096);
        char* lb = (char*)&Bs[buf][0];
#pragma unroll
        for (int r = 0; r < 2; ++r) {
            const char* g = tb + (r * 256 + t) * 16;
            unsigned ldsoff = (unsigned)((r * 256 + wid * 64) * 16);  // wave-uniform
            __builtin_amdgcn_global_load_lds(
                (const __attribute__((address_space(1))) unsigned int*)g,
                (__attribute__((address_space(3))) unsigned int*)(lb + ldsoff),
                16, 0, 0);
        }
    };

    // per-thread fragment address constants
    int abyte[4], a7[4];
#pragma unroll
    for (int mi = 0; mi < 4; ++mi) {
        int m = wm * 64 + mi * 16 + l15;
        abyte[mi] = m * 128;
        a7[mi] = m & 7;
    }
    int nbyte[2], n7[2];
#pragma unroll
    for (int ni = 0; ni < 2; ++ni) {
        int n = wn * 32 + ni * 16 + l15;
        nbyte[ni] = n * 128;
        n7[ni] = n & 7;
    }

    f32x4 acc[4][2] = {};

    // ---- prologue: x(0) -> stageB(0) -> x(1) -> stageA(0) -> wait -> barrier
    float2 x1 = *reinterpret_cast<const float2*>(xp);       // x for tile 0
    stageB(0, 0);
    float2 xn = *reinterpret_cast<const float2*>(xp + 4);   // x for tile 1
    stageA(0, x1);
    x1 = xn;
    asm volatile("s_waitcnt vmcnt(1) lgkmcnt(0)" ::: "memory");
    __builtin_amdgcn_s_barrier();
    __builtin_amdgcn_sched_barrier(0);

    auto ITER = [&](int tt, int cur) {
        const bool last = (tt == ITERS - 1);
        if (!last) {
            stageB(cur ^ 1, tt + 1);                        // 2 VMEM (counted)
            int xi = (tt + 2 < ITERS) ? tt + 2 : ITERS - 1; // keep count constant
            xn = *reinterpret_cast<const float2*>(xp + xi * 4);  // 1 VMEM
        }

        // fragment reads: 12 x ds_read_b128
        bf16x8 af[4][2], bg[2][2];
        const char* Ab = (const char*)&As[cur][0];
        const char* Bb = (const char*)&Bs[cur][0];
#pragma unroll
        for (int kh = 0; kh < 2; ++kh) {
            int k8 = kh * 4 + lhi;
#pragma unroll
            for (int mi = 0; mi < 4; ++mi)
                af[mi][kh] = *reinterpret_cast<const bf16x8*>(
                    Ab + abyte[mi] + ((k8 ^ a7[mi]) << 4));
#pragma unroll
            for (int ni = 0; ni < 2; ++ni)
                bg[ni][kh] = *reinterpret_cast<const bf16x8*>(
                    Bb + nbyte[ni] + ((k8 ^ n7[ni]) << 4));
        }

        // A-build for next tile (VALU overlaps ds_read latency + B-DMA)
        if (!last) stageA(cur ^ 1, x1);

        // 16 MFMA
#pragma unroll
        for (int mi = 0; mi < 4; ++mi)
#pragma unroll
            for (int ni = 0; ni < 2; ++ni)
#pragma unroll
                for (int kh = 0; kh < 2; ++kh)
                    acc[mi][ni] = __builtin_amdgcn_mfma_f32_16x16x32_bf16(
                        af[mi][kh], bg[ni][kh], acc[mi][ni], 0, 0, 0);

        if (!last) {
            x1 = xn;
            // wait: B(t+1) DMA done (vmcnt(1) leaves x-prefetch in flight),
            // A(t+1) ds_writes done (lgkmcnt(0)); then raw barrier - no
            // vmcnt(0) drain, x-load stays airborne across it.
            asm volatile("s_waitcnt vmcnt(1) lgkmcnt(0)" ::: "memory");
            __builtin_amdgcn_s_barrier();
            __builtin_amdgcn_sched_barrier(0);
        }
    };

    for (int tt = 0; tt < ITERS / 2; ++tt) {
        ITER(2 * tt,     0);
        ITER(2 * tt + 1, 1);
    }

    // ---- epilogue: + skip_b, direct coalesced-ish stores (no atomics)
#pragma unroll
    for (int ni = 0; ni < 2; ++ni) {
        int col = oc0 + wn * 32 + ni * 16 + l15;
        float sb = skip_b[col];
#pragma unroll
        for (int mi = 0; mi < 4; ++mi) {
            f32x4 v = acc[mi][ni];
            int row0 = bm0 + wm * 64 + mi * 16 + lhi * 4;
#pragma unroll
            for (int r = 0; r < 4; ++r)
                out[(size_t)(row0 + r) * O_DIM + col] = v[r] + sb;
        }
    }
}

extern "C" void kernel_launch(void* const* d_in, const int* in_sizes, int n_in,
                              void* d_out, int out_size, void* d_ws, size_t ws_size,
                              hipStream_t stream) {
    const float* x      = (const float*)d_in[0];   // [8192][256]
    const float* values = (const float*)d_in[1];   // [256][256][16]
    const float* skip_w = (const float*)d_in[2];   // [256][256]
    const float* skip_b = (const float*)d_in[3];   // [256]
    const float* gknots = (const float*)d_in[4];   // [16]
    float* out = (float*)d_out;
    unsigned short* Vp = (unsigned short*)d_ws;    // 2 MB bf16 scratch
    (void)in_sizes; (void)n_in; (void)out_size; (void)ws_size;

    // Prep: 1,048,576 elements, 8 per thread
    kan_prep<<<dim3(512), dim3(256), 0, stream>>>(values, skip_w, gknots, Vp);

    // GEMM: 64 M-tiles x 4 N-tiles = 256 blocks (1/CU), no K-split
    kan_gemm<<<dim3(256), dim3(NTHREADS), 0, stream>>>(x, Vp, skip_b, out);
}

// Round 6
// 41.433 us; speedup vs baseline: 1.7547x; 1.5156x over previous
//
#include <hip/hip_runtime.h>
#include <hip/hip_bf16.h>
#include <stdint.h>

// KANLinear: y[b,o] = sum_{d,k} coeff[b,d,k]*values[o,d,k] + xc@skip_w^T + skip_b
//   Vp[o,d*16+k] = values[o,d,k] + grid[k]*skip_w[o,d]   (prep, bf16)
//   y = A @ Vp^T + skip_b  (MFMA GEMM  M=8192 N=256 K=4096)
// Round 6: B-fragments DIRECT from L2 (Vp chunk-transposed, no B-LDS);
//          BN=256 (A staged once, no cross-block dup), BM=128, 8 waves of
//          64x64; KSPLIT=4 -> workspace partials + reduce kernel (no atomics);
//          1 raw barrier/iter (lgkmcnt only, vmcnt never drained).

#define D_DIM  256
#define O_DIM  256
#define BM     128
#define BK     64
#define NTHR   512

typedef __attribute__((ext_vector_type(8))) short bf16x8;
typedef __attribute__((ext_vector_type(4))) float f32x4;

// ---------------------------------------------------------------------------
// Prep: Vp chunk-transposed: chunk c = kflat>>3 (0..511), store at
// Vp[(c*256 + o)*8 .. +8) so a GEMM B-fragment (16 consecutive n at one c)
// is a 256B-coalesced global_load_dwordx4 per 16-lane group.
// ---------------------------------------------------------------------------
__global__ __launch_bounds__(256) void kan_prep(
    const float* __restrict__ values,   // [O][D][K]
    const float* __restrict__ skip_w,   // [O][D]
    const float* __restrict__ gknots,   // [K]
    unsigned short* __restrict__ Vp)    // 2 MB bf16, chunk-transposed
{
    int tid = blockIdx.x * blockDim.x + threadIdx.x;    // 0..131071
    int e = tid * 8;
    int o = e >> 12;
    int kflat = e & 4095;
    float sw = skip_w[(o << 8) | (kflat >> 4)];
    int kmod = kflat & 15;                              // 0 or 8

    const float4* vp4 = reinterpret_cast<const float4*>(values + e);
    float4 v0 = vp4[0], v1 = vp4[1];
    float f[8] = {v0.x, v0.y, v0.z, v0.w, v1.x, v1.y, v1.z, v1.w};
    unsigned int w[4];
#pragma unroll
    for (int j = 0; j < 4; ++j) {
        float2 ab;
        ab.x = f[2*j]     + gknots[kmod + 2*j]     * sw;
        ab.y = f[2*j + 1] + gknots[kmod + 2*j + 1] * sw;
        __hip_bfloat162 p2 = __float22bfloat162_rn(ab);
        __builtin_memcpy(&w[j], &p2, 4);
    }
    // two chunks per thread (8 elems = 1 chunk)  -> actually 8 elems = exactly
    // one 16B chunk: c = kflat>>3
    size_t c = (size_t)(kflat >> 3) * 256 + (size_t)o;
    *reinterpret_cast<uint4*>(Vp + c * 8) = make_uint4(w[0], w[1], w[2], w[3]);
}

// ---------------------------------------------------------------------------
// GEMM: BM=128 x BN=256(all of O) x BK=64, 512 thr = 8 waves (2m x 4n),
// wave-tile 64x64 (acc[4][4]). A via LDS dbuf (XOR swizzle, 2x16KB);
// B direct global->reg prefetch. Writes f32 partial for its K-slice.
// ---------------------------------------------------------------------------
template<int KS>
__global__ __launch_bounds__(NTHR, 2) void kan_gemm(
    const float* __restrict__ x,          // [B][D] f32
    const unsigned short* __restrict__ Vp,
    float* __restrict__ part)             // [KS][8192][256] f32
{
    __shared__ unsigned short As[2][BM * BK];   // 2 x 16 KB

    constexpr int ITERS = 64 / KS;              // BK-tiles per slice
    const int t    = threadIdx.x;
    const int lane = t & 63;
    const int wid  = t >> 6;
    const int wm   = wid >> 2;         // 0..1  (64 rows each)
    const int wn   = wid & 3;          // 0..3  (64 cols each)
    const int l15  = lane & 15;
    const int lhi  = lane >> 4;        // 0..3

    const int bid = (int)blockIdx.x;
    const int ks  = bid & (KS - 1);
    const int mt  = bid / KS;
    const int bm0 = mt * BM;
    const size_t kc0 = (size_t)ks * (512 / KS);   // global 16B-chunk base

    // A staging: thread -> row ar (0..127), d-local ad (0..3)
    const int ar = t >> 2;
    const int ad = t & 3;
    const float* xp = x + (size_t)(bm0 + ar) * D_DIM + ks * (256 / KS) + ad;

    char* arow[2] = { (char*)&As[0][0] + ar * 128, (char*)&As[1][0] + ar * 128 };
    const int ca = ((2 * ad)     ^ (ar & 7)) * 16;
    const int cb = ((2 * ad + 1) ^ (ar & 7)) * 16;

    // one x value -> 16 bf16 interp coeffs (8 dwords), pair at knots li,li+1
    auto stageA = [&](int buf, float xv) {
        float xc = fminf(1.f, fmaxf(-1.f, xv));
        float tt = (xc + 1.f) * 7.5f;            // (xc - g0)/h, h = 2/15
        int li = (int)tt;
        li = li > 14 ? 14 : li;
        float w1 = tt - (float)li;
        float2 cw; cw.x = 1.f - w1; cw.y = w1;
        __hip_bfloat162 p2 = __float22bfloat162_rn(cw);   // v_cvt_pk_bf16_f32
        unsigned int pk;
        __builtin_memcpy(&pk, &p2, 4);
        unsigned long long w64 = (unsigned long long)pk << ((li & 1) * 16);
        unsigned int lo = (unsigned int)w64;
        unsigned int hi = (unsigned int)(w64 >> 32);
        int jl = li >> 1;
        unsigned int wd[8];
#pragma unroll
        for (int j = 0; j < 8; ++j)
            wd[j] = (j == jl) ? lo : ((j == jl + 1) ? hi : 0u);
        char* a = arow[buf];
        *reinterpret_cast<uint4*>(a + ca) = make_uint4(wd[0], wd[1], wd[2], wd[3]);
        *reinterpret_cast<uint4*>(a + cb) = make_uint4(wd[4], wd[5], wd[6], wd[7]);
    };

    // B fragment loads: frag (kh, ni) at chunk kc0 + kt*8 + kh*4 + lhi,
    // column n = wn*64 + ni*16 + l15.
    #define LOADB(BG, KT)                                                      \
        {                                                                      \
            const unsigned short* _b =                                         \
                Vp + (kc0 + (size_t)(KT) * 8) * 2048;                          \
            _Pragma("unroll")                                                  \
            for (int kh = 0; kh < 2; ++kh)                                     \
                _Pragma("unroll")                                              \
                for (int ni = 0; ni < 4; ++ni) {                               \
                    int n = wn * 64 + ni * 16 + l15;                           \
                    BG[kh * 4 + ni] = *reinterpret_cast<const bf16x8*>(        \
                        _b + ((size_t)((kh * 4 + lhi) * 256 + n)) * 8);        \
                }                                                              \
        }

    f32x4 acc[4][4] = {};
    bf16x8 bgA[8], bgB[8];

    // per-thread A-read constants
    int abyte[4], a7[4];
#pragma unroll
    for (int mi = 0; mi < 4; ++mi) {
        int m = wm * 64 + mi * 16 + l15;
        abyte[mi] = m * 128;
        a7[mi] = m & 7;
    }

    // ---- prologue: B(0)->bgA, stage A(0), prefetch x(1)
    float xnxt = xp[0];
    LOADB(bgA, 0);
    stageA(0, xnxt);
    xnxt = (ITERS > 1) ? xp[4] : xnxt;
    asm volatile("s_waitcnt lgkmcnt(0)" ::: "memory");
    __builtin_amdgcn_s_barrier();
    __builtin_amdgcn_sched_barrier(0);

    // ---- main loop: two iters per body for static double-buffer naming
    #define ITERBODY(KT, CUR, BGC, BGN)                                        \
        {                                                                      \
            const bool last = (KT) == ITERS - 1;                               \
            if (!last) LOADB(BGN, (KT) + 1);                                   \
            const char* Ab = (const char*)&As[CUR][0];                         \
            bf16x8 af[4];                                                      \
            /* kh = 0 */                                                       \
            _Pragma("unroll")                                                  \
            for (int mi = 0; mi < 4; ++mi)                                     \
                af[mi] = *reinterpret_cast<const bf16x8*>(                     \
                    Ab + abyte[mi] + ((lhi ^ a7[mi]) << 4));                   \
            _Pragma("unroll")                                                  \
            for (int mi = 0; mi < 4; ++mi)                                     \
                _Pragma("unroll")                                              \
                for (int ni = 0; ni < 4; ++ni)                                 \
                    acc[mi][ni] = __builtin_amdgcn_mfma_f32_16x16x32_bf16(     \
                        af[mi], BGC[ni], acc[mi][ni], 0, 0, 0);                \
            /* stage next A while kh=1 reads queue */                          \
            if (!last) {                                                       \
                stageA((CUR) ^ 1, xnxt);                                       \
                if ((KT) + 2 < ITERS) xnxt = xp[((KT) + 2) * 4];               \
            }                                                                  \
            /* kh = 1 */                                                       \
            _Pragma("unroll")                                                  \
            for (int mi = 0; mi < 4; ++mi)                                     \
                af[mi] = *reinterpret_cast<const bf16x8*>(                     \
                    Ab + abyte[mi] + (((4 + lhi) ^ a7[mi]) << 4));             \
            _Pragma("unroll")                                                  \
            for (int mi = 0; mi < 4; ++mi)                                     \
                _Pragma("unroll")                                              \
                for (int ni = 0; ni < 4; ++ni)                                 \
                    acc[mi][ni] = __builtin_amdgcn_mfma_f32_16x16x32_bf16(     \
                        af[mi], BGC[4 + ni], acc[mi][ni], 0, 0, 0);            \
            if (!last) {                                                       \
                asm volatile("s_waitcnt lgkmcnt(0)" ::: "memory");             \
                __builtin_amdgcn_s_barrier();                                  \
                __builtin_amdgcn_sched_barrier(0);                             \
            }                                                                  \
        }

    for (int t2 = 0; t2 < ITERS / 2; ++t2) {
        ITERBODY(2 * t2,     0, bgA, bgB);
        ITERBODY(2 * t2 + 1, 1, bgB, bgA);
    }
    #undef ITERBODY
    #undef LOADB

    // ---- epilogue: partial store (bias added in reduce)
    float* dst = part + (size_t)ks * (8192 * 256);
#pragma unroll
    for (int ni = 0; ni < 4; ++ni) {
        int col = wn * 64 + ni * 16 + l15;
#pragma unroll
        for (int mi = 0; mi < 4; ++mi) {
            f32x4 v = acc[mi][ni];
            int row0 = bm0 + wm * 64 + mi * 16 + lhi * 4;
#pragma unroll
            for (int r = 0; r < 4; ++r)
                dst[(size_t)(row0 + r) * O_DIM + col] = v[r];
        }
    }
}

// ---------------------------------------------------------------------------
// Reduce: out = sum_p part[p] + skip_b  (vectorized f32x4)
// ---------------------------------------------------------------------------
__global__ __launch_bounds__(256) void kan_reduce(
    const float* __restrict__ part,   // [nparts][8192][256]
    const float* __restrict__ skip_b, // [256]
    float* __restrict__ out,          // [8192][256]
    int nparts)
{
    size_t i4 = (size_t)blockIdx.x * 256 + threadIdx.x;   // float4 index
    size_t e = i4 * 4;
    f32x4 s = *reinterpret_cast<const f32x4*>(&skip_b[e & 255]);
    for (int p = 0; p < nparts; ++p)
        s += *reinterpret_cast<const f32x4*>(part + (size_t)p * (8192 * 256) + e);
    *reinterpret_cast<f32x4*>(out + e) = s;
}

extern "C" void kernel_launch(void* const* d_in, const int* in_sizes, int n_in,
                              void* d_out, int out_size, void* d_ws, size_t ws_size,
                              hipStream_t stream) {
    const float* x      = (const float*)d_in[0];   // [8192][256]
    const float* values = (const float*)d_in[1];   // [256][256][16]
    const float* skip_w = (const float*)d_in[2];   // [256][256]
    const float* skip_b = (const float*)d_in[3];   // [256]
    const float* gknots = (const float*)d_in[4];   // [16]
    float* out = (float*)d_out;
    (void)in_sizes; (void)n_in; (void)out_size;

    unsigned short* Vp = (unsigned short*)d_ws;                    // 2 MB
    float* part = (float*)((char*)d_ws + 2 * 1024 * 1024);         // partials

    kan_prep<<<dim3(512), dim3(256), 0, stream>>>(values, skip_w, gknots, Vp);

    const size_t need4 = 2u * 1024 * 1024 + (size_t)4 * 8192 * 256 * 4;
    if (ws_size >= need4) {
        // 64 M-tiles x 4 K-splits = 256 blocks x 512 thr = 1 block/CU, 2 w/SIMD
        kan_gemm<4><<<dim3(256), dim3(NTHR), 0, stream>>>(x, Vp, part);
        kan_reduce<<<dim3(2048), dim3(256), 0, stream>>>(part, skip_b, out, 4);
    } else {
        // fallback: no K-split; partial lives in out, reduce adds bias in-place
        kan_gemm<1><<<dim3(64), dim3(NTHR), 0, stream>>>(x, Vp, out);
        kan_reduce<<<dim3(2048), dim3(256), 0, stream>>>(out, skip_b, out, 1);
    }
}